// Round 6
// baseline (121.411 us; speedup 1.0000x reference)
//
// v6: W staged in LDS (kills the per-iter s_load serialization), 256-thr
// blocks / 32 cols -> grid 784 (3.06 blk/CU, balanced), LDS buffer reused
// for partials after sync. Distance-2 x prefetch kept. k_conv unchanged.
#include <hip/hip_runtime.h>

#define T 8
#define C 512
#define HW 196
#define NSEG 16                  // n
#define NT (NSEG * T)            // 128
#define NCOL (NT * HW)           // 25088 (nt, hw) columns
#define B_TOT (NSEG * HW)        // 3136
#define NH 4
#define KK 5
#define NO 20                    // NH*KK
#define S_SPLIT 8                // channel chunks per block
#define CCH (C / S_SPLIT)        // 64 channels per chunk
#define COLS 32                  // columns per k_weights block
#define WFL (NO * C)             // 10240 floats of W = 40 KB

// ---------------------------------------------------------------------------
// Kernel 1: fused logits + LDS chunk-reduction + softmax -> weights.
// 256 threads = 8 chunks x 32 cols. W lives in LDS (ds_read broadcast,
// 2 unique addrs/wave = free aliasing); same 40 KB is reused for the
// partial-logit reduction after the main loop.
// ---------------------------------------------------------------------------
__global__ __launch_bounds__(256) void k_weights(const float* __restrict__ x,
                                                 const float* __restrict__ W,
                                                 float* __restrict__ wgt) {
    __shared__ float smem[WFL];                 // 40 KB: W, then partials

    const int tid = threadIdx.x;

    // ---- stage W: 10240 floats = 256 threads x 10 float4 (coalesced) ----
    {
        const float4* Wg = (const float4*)W;
        float4*       Ws = (float4*)smem;
#pragma unroll
        for (int k = 0; k < 10; ++k)
            Ws[tid + k * 256] = Wg[tid + k * 256];
    }
    __syncthreads();

    const int col  = tid & 31;                  // column within tile
    const int sch  = tid >> 5;                  // channel chunk 0..7
    const int cbase = sch * CCH;

    const int idx = blockIdx.x * COLS + col;    // flattened (nt, hw)
    const int nt  = idx / HW;
    const int hw  = idx - nt * HW;

    const float* xp = x + ((size_t)nt * C + cbase) * HW + hw;

    float acc[NO];
#pragma unroll
    for (int o = 0; o < NO; ++o) acc[o] = 0.f;

    // distance-2 software pipeline on the x loads
    float xa[8], xb[8], xc[8];
#pragma unroll
    for (int u = 0; u < 8; ++u) xa[u] = xp[u * HW];
#pragma unroll
    for (int u = 0; u < 8; ++u) xb[u] = xp[(8 + u) * HW];

#pragma unroll
    for (int c0 = 0; c0 < CCH; c0 += 8) {
        if (c0 + 16 < CCH) {
#pragma unroll
            for (int u = 0; u < 8; ++u) xc[u] = xp[(c0 + 16 + u) * HW];
        }
        const float* wl = smem + cbase + c0;    // W slice for this chunk
#pragma unroll
        for (int o = 0; o < NO; ++o) {
            const float4 w0 = *(const float4*)(wl + o * C);
            const float4 w1 = *(const float4*)(wl + o * C + 4);
            acc[o] = fmaf(xa[0], w0.x, acc[o]);
            acc[o] = fmaf(xa[1], w0.y, acc[o]);
            acc[o] = fmaf(xa[2], w0.z, acc[o]);
            acc[o] = fmaf(xa[3], w0.w, acc[o]);
            acc[o] = fmaf(xa[4], w1.x, acc[o]);
            acc[o] = fmaf(xa[5], w1.y, acc[o]);
            acc[o] = fmaf(xa[6], w1.z, acc[o]);
            acc[o] = fmaf(xa[7], w1.w, acc[o]);
        }
#pragma unroll
        for (int u = 0; u < 8; ++u) { xa[u] = xb[u]; xb[u] = xc[u]; }
    }

    // ---- reuse smem for partials (all W reads are done) ----
    __syncthreads();
#pragma unroll
    for (int o = 0; o < NO; ++o)
        smem[(sch * NO + o) * COLS + col] = acc[o];
    __syncthreads();

    // reduce over chunks (s-order 0..7, same as always -> identical
    // numerics), softmax over 5 taps. 128 threads: (head 0..3) x (col 0..31).
    if (tid < COLS * NH) {
        const int c2   = tid & 31;
        const int h    = tid >> 5;
        const int idx2 = blockIdx.x * COLS + c2;
        const int nt2  = idx2 / HW;
        const int hw2  = idx2 - nt2 * HW;
        const int t    = nt2 & (T - 1);
        const int n    = nt2 / T;
        const int b    = n * HW + hw2;

        float lg[KK];
#pragma unroll
        for (int k = 0; k < KK; ++k) {
            float sm = 0.f;
#pragma unroll
            for (int s2 = 0; s2 < S_SPLIT; ++s2)
                sm += smem[(s2 * NO + h * KK + k) * COLS + c2];
            lg[k] = sm;
        }

        float m = lg[0];
#pragma unroll
        for (int k = 1; k < KK; ++k) m = fmaxf(m, lg[k]);
        float e[KK];
        float sum = 0.f;
#pragma unroll
        for (int k = 0; k < KK; ++k) {
            e[k] = __expf(lg[k] - m);
            sum += e[k];
        }
        const float r = 1.f / sum;
#pragma unroll
        for (int k = 0; k < KK; ++k)
            wgt[((size_t)((t * NH + h) * KK + k)) * B_TOT + b] = e[k] * r;
    }
}

// ---------------------------------------------------------------------------
// Kernel 2: causal dynamic conv, one thread per (n, c, hw). Unchanged —
// at its ~8 µs floor (x re-read is L3-hot right after k_weights).
// ---------------------------------------------------------------------------
__global__ __launch_bounds__(256) void k_conv(const float* __restrict__ x,
                                              const float* __restrict__ wgt,
                                              float* __restrict__ out) {
    const int idx = blockIdx.x * 256 + threadIdx.x;  // < 16*512*196
    const int hw  = idx % HW;
    const int t1  = idx / HW;          // n*C + c
    const int c   = t1 % C;
    const int n   = t1 / C;
    const int h   = c >> 7;            // head
    const int b   = n * HW + hw;

    float w[T][KK];
#pragma unroll
    for (int t = 0; t < T; ++t)
#pragma unroll
        for (int k = 0; k < KK; ++k)
            w[t][k] = wgt[((size_t)((t * NH + h) * KK + k)) * B_TOT + b];

    const size_t base = ((size_t)(n * T) * C + c) * HW + hw;
    float xv[T];
#pragma unroll
    for (int t = 0; t < T; ++t) xv[t] = x[base + (size_t)t * C * HW];

#pragma unroll
    for (int t = 0; t < T; ++t) {
        float acc = 0.f;
#pragma unroll
        for (int k = 0; k < KK; ++k) {
            const int j = t + k - 4;   // causal, zero-padded left
            if (j >= 0) acc = fmaf(w[t][k], xv[j], acc);
        }
        out[base + (size_t)t * C * HW] = acc;
    }
}

// ---------------------------------------------------------------------------
extern "C" void kernel_launch(void* const* d_in, const int* in_sizes, int n_in,
                              void* d_out, int out_size, void* d_ws, size_t ws_size,
                              hipStream_t stream) {
    const float* x = (const float*)d_in[0];   // (128, 512, 14, 14)
    const float* W = (const float*)d_in[1];   // (20, 512)
    float* out = (float*)d_out;               // (128, 512, 14, 14)

    float* wgt = (float*)d_ws;                // 160 * 3136 floats = 2 MB

    k_weights<<<dim3(NCOL / COLS), 256, 0, stream>>>(x, W, wgt);
    k_conv<<<dim3((NSEG * C * HW) / 256), 256, 0, stream>>>(x, wgt, out);
}

// Round 7
// 119.485 us; speedup vs baseline: 1.0161x; 1.0161x over previous
//
// v7: k_weights = v4 verbatim (proven best: wave-uniform scalar-W, dist-1
// prefetch). k_conv vectorized float2 along hw: 28 vector accesses/thread
// instead of 56 scalar -> half the issue, 8 B/lane coalescing sweet spot.
#include <hip/hip_runtime.h>

#define T 8
#define C 512
#define HW 196
#define HW2 (HW / 2)             // 98 float2 per (nt, c)
#define NSEG 16                  // n
#define NT (NSEG * T)            // 128
#define NCOL (NT * HW)           // 25088 (nt, hw) columns
#define B_TOT (NSEG * HW)        // 3136
#define NH 4
#define KK 5
#define NO 20                    // NH*KK
#define S_SPLIT 8                // channel chunks = waves per block
#define CCH (C / S_SPLIT)        // 64 channels per chunk
#define COLS 64                  // columns per k_weights block (= lanes)

// ---------------------------------------------------------------------------
// Kernel 1: fused logits + LDS chunk-reduction + softmax -> weights.
// Grid 392 x 512. Wave w = channel chunk w (W via s_load, readfirstlane-
// pinned). Dist-1 prefetch on x (proven sufficient: dist-2 was neutral).
// ---------------------------------------------------------------------------
__global__ __launch_bounds__(512) void k_weights(const float* __restrict__ x,
                                                 const float* __restrict__ W,
                                                 float* __restrict__ wgt) {
    __shared__ float plds[S_SPLIT][NO][COLS];   // 40960 B

    const int tid  = threadIdx.x;
    const int lane = tid & 63;                  // column within tile
    const int sch  = tid >> 6;                  // wave index = channel chunk
    const int cbase = __builtin_amdgcn_readfirstlane(sch * CCH);  // SGPR

    const int idx = blockIdx.x * COLS + lane;   // flattened (nt, hw)
    const int nt  = idx / HW;
    const int hw  = idx - nt * HW;

    const float* xp = x + ((size_t)nt * C + cbase) * HW + hw;
    const float* Wb = W + cbase;                // wave-uniform base -> s_load

    float acc[NO];
#pragma unroll
    for (int o = 0; o < NO; ++o) acc[o] = 0.f;

    float xv[8], xn[8];
#pragma unroll
    for (int u = 0; u < 8; ++u) xv[u] = xp[u * HW];

#pragma unroll
    for (int c0 = 0; c0 < CCH; c0 += 8) {
        if (c0 + 8 < CCH) {
#pragma unroll
            for (int u = 0; u < 8; ++u) xn[u] = xp[(c0 + 8 + u) * HW];
        }
        const float* wr = Wb + c0;              // wave-uniform
#pragma unroll
        for (int o = 0; o < NO; ++o) {
#pragma unroll
            for (int u = 0; u < 8; ++u)
                acc[o] = fmaf(xv[u], wr[o * C + u], acc[o]);
        }
#pragma unroll
        for (int u = 0; u < 8; ++u) xv[u] = xn[u];
    }

    // partials: lane-consecutive -> 2-way bank aliasing max (free on CDNA4)
#pragma unroll
    for (int o = 0; o < NO; ++o) plds[sch][o][lane] = acc[o];
    __syncthreads();

    // reduce over chunks (s-order 0..7 -> identical numerics), softmax over
    // 5 taps. 256 threads: (head 0..3) x (col 0..63).
    if (tid < COLS * NH) {
        const int col  = tid & 63;
        const int h    = tid >> 6;
        const int idx2 = blockIdx.x * COLS + col;
        const int nt2  = idx2 / HW;
        const int hw2  = idx2 - nt2 * HW;
        const int t    = nt2 & (T - 1);
        const int n    = nt2 / T;
        const int b    = n * HW + hw2;

        float lg[KK];
#pragma unroll
        for (int k = 0; k < KK; ++k) {
            float sm = 0.f;
#pragma unroll
            for (int s2 = 0; s2 < S_SPLIT; ++s2)
                sm += plds[s2][h * KK + k][col];
            lg[k] = sm;
        }

        float m = lg[0];
#pragma unroll
        for (int k = 1; k < KK; ++k) m = fmaxf(m, lg[k]);
        float e[KK];
        float sum = 0.f;
#pragma unroll
        for (int k = 0; k < KK; ++k) {
            e[k] = __expf(lg[k] - m);
            sum += e[k];
        }
        const float r = 1.f / sum;
#pragma unroll
        for (int k = 0; k < KK; ++k)
            wgt[((size_t)((t * NH + h) * KK + k)) * B_TOT + b] = e[k] * r;
    }
}

// ---------------------------------------------------------------------------
// Kernel 2: causal dynamic conv, one thread per (n, c, hw-pair). float2
// everywhere along hw: 28 vector mem-ops/thread vs 56 scalar before.
// Same per-element arithmetic and order -> bitwise-identical results.
// ---------------------------------------------------------------------------
__global__ __launch_bounds__(256) void k_conv(const float* __restrict__ x,
                                              const float* __restrict__ wgt,
                                              float* __restrict__ out) {
    const int idx = blockIdx.x * 256 + threadIdx.x;  // < 16*512*98
    const int q   = idx % HW2;
    const int t1  = idx / HW2;         // n*C + c
    const int c   = t1 % C;
    const int n   = t1 / C;
    const int h   = c >> 7;            // head
    const int hw  = q * 2;
    const int b   = n * HW + hw;

    float2 w[T][KK];
#pragma unroll
    for (int t = 0; t < T; ++t)
#pragma unroll
        for (int k = 0; k < KK; ++k)
            w[t][k] = *(const float2*)&wgt[((size_t)((t * NH + h) * KK + k)) * B_TOT + b];

    const size_t base = ((size_t)(n * T) * C + c) * HW + hw;
    float2 xv[T];
#pragma unroll
    for (int t = 0; t < T; ++t) xv[t] = *(const float2*)&x[base + (size_t)t * C * HW];

#pragma unroll
    for (int t = 0; t < T; ++t) {
        float2 acc = make_float2(0.f, 0.f);
#pragma unroll
        for (int k = 0; k < KK; ++k) {
            const int j = t + k - 4;   // causal, zero-padded left
            if (j >= 0) {
                acc.x = fmaf(w[t][k].x, xv[j].x, acc.x);
                acc.y = fmaf(w[t][k].y, xv[j].y, acc.y);
            }
        }
        *(float2*)&out[base + (size_t)t * C * HW] = acc;
    }
}

// ---------------------------------------------------------------------------
extern "C" void kernel_launch(void* const* d_in, const int* in_sizes, int n_in,
                              void* d_out, int out_size, void* d_ws, size_t ws_size,
                              hipStream_t stream) {
    const float* x = (const float*)d_in[0];   // (128, 512, 14, 14)
    const float* W = (const float*)d_in[1];   // (20, 512)
    float* out = (float*)d_out;               // (128, 512, 14, 14)

    float* wgt = (float*)d_ws;                // 160 * 3136 floats = 2 MB

    k_weights<<<dim3(NCOL / COLS), 512, 0, stream>>>(x, W, wgt);
    k_conv<<<dim3((NSEG * C * HW2) / 256), 256, 0, stream>>>(x, wgt, out);
}

// Round 8
// 117.103 us; speedup vs baseline: 1.0368x; 1.0203x over previous
//
// v8: k_weights retiled COLS=49 -> grid 512 = exactly 2 blocks/CU (was 392
// = 1.53/CU with a 2:1 second round). 4 waves/SIMD hides scalar/vmem
// latency. nt is block-uniform (49*4=196). k_conv = v4 scalar (proven best).
#include <hip/hip_runtime.h>

#define T 8
#define C 512
#define HW 196
#define NSEG 16                  // n
#define NT (NSEG * T)            // 128
#define B_TOT (NSEG * HW)        // 3136
#define NH 4
#define KK 5
#define NO 20                    // NH*KK
#define S_SPLIT 8                // channel chunks = waves per block
#define CCH (C / S_SPLIT)        // 64 channels per chunk
#define COLS 49                  // columns per block: 25088/49 = 512 blocks
#define LDSC 64                  // padded col dim for LDS (lanes 49..63 park)

// ---------------------------------------------------------------------------
// Kernel 1: fused logits + LDS chunk-reduction + softmax -> weights.
// Grid 512 x 512thr. Wave w = channel chunk w (W via s_load, readfirstlane-
// pinned). Each block owns one nt and a 49-wide hw strip.
// ---------------------------------------------------------------------------
__global__ __launch_bounds__(512, 4) void k_weights(const float* __restrict__ x,
                                                    const float* __restrict__ W,
                                                    float* __restrict__ wgt) {
    __shared__ float plds[S_SPLIT][NO][LDSC];   // 40960 B

    const int tid  = threadIdx.x;
    const int lane = tid & 63;
    const int sch  = tid >> 6;                  // wave index = channel chunk
    const int cbase = __builtin_amdgcn_readfirstlane(sch * CCH);  // SGPR

    const int nt  = blockIdx.x >> 2;            // block-uniform
    const int hw0 = (blockIdx.x & 3) * COLS;
    const int hw  = hw0 + (lane < COLS ? lane : COLS - 1);  // clamp: in-bounds

    const float* xp = x + ((size_t)nt * C + cbase) * HW + hw;
    const float* Wb = W + cbase;                // wave-uniform base -> s_load

    float acc[NO];
#pragma unroll
    for (int o = 0; o < NO; ++o) acc[o] = 0.f;

    float xv[8], xn[8];
#pragma unroll
    for (int u = 0; u < 8; ++u) xv[u] = xp[u * HW];

#pragma unroll
    for (int c0 = 0; c0 < CCH; c0 += 8) {
        if (c0 + 8 < CCH) {
#pragma unroll
            for (int u = 0; u < 8; ++u) xn[u] = xp[(c0 + 8 + u) * HW];
        }
        const float* wr = Wb + c0;              // wave-uniform
#pragma unroll
        for (int o = 0; o < NO; ++o) {
#pragma unroll
            for (int u = 0; u < 8; ++u)
                acc[o] = fmaf(xv[u], wr[o * C + u], acc[o]);
        }
#pragma unroll
        for (int u = 0; u < 8; ++u) xv[u] = xn[u];
    }

    // partials: lane-consecutive -> 2-way bank aliasing max (free on CDNA4)
#pragma unroll
    for (int o = 0; o < NO; ++o) plds[sch][o][lane] = acc[o];
    __syncthreads();

    // reduce over chunks (s-order 0..7 -> numerics identical to v4),
    // softmax over 5 taps. 196 threads: (head 0..3) x (col 0..48).
    if (tid < COLS * NH) {
        const int h   = tid / COLS;
        const int col = tid - h * COLS;
        const int t   = nt & (T - 1);
        const int n   = nt >> 3;                // nt / T
        const int b   = n * HW + hw0 + col;

        float lg[KK];
#pragma unroll
        for (int k = 0; k < KK; ++k) {
            float sm = 0.f;
#pragma unroll
            for (int s2 = 0; s2 < S_SPLIT; ++s2)
                sm += plds[s2][h * KK + k][col];
            lg[k] = sm;
        }

        float m = lg[0];
#pragma unroll
        for (int k = 1; k < KK; ++k) m = fmaxf(m, lg[k]);
        float e[KK];
        float sum = 0.f;
#pragma unroll
        for (int k = 0; k < KK; ++k) {
            e[k] = __expf(lg[k] - m);
            sum += e[k];
        }
        const float r = 1.f / sum;
#pragma unroll
        for (int k = 0; k < KK; ++k)
            wgt[((size_t)((t * NH + h) * KK + k)) * B_TOT + b] = e[k] * r;
    }
}

// ---------------------------------------------------------------------------
// Kernel 2: causal dynamic conv, one thread per (n, c, hw) — v4 scalar
// version verbatim (float2 variant measured +3 µs worse).
// ---------------------------------------------------------------------------
__global__ __launch_bounds__(256) void k_conv(const float* __restrict__ x,
                                              const float* __restrict__ wgt,
                                              float* __restrict__ out) {
    const int idx = blockIdx.x * 256 + threadIdx.x;  // < 16*512*196
    const int hw  = idx % HW;
    const int t1  = idx / HW;          // n*C + c
    const int c   = t1 % C;
    const int n   = t1 / C;
    const int h   = c >> 7;            // head
    const int b   = n * HW + hw;

    float w[T][KK];
#pragma unroll
    for (int t = 0; t < T; ++t)
#pragma unroll
        for (int k = 0; k < KK; ++k)
            w[t][k] = wgt[((size_t)((t * NH + h) * KK + k)) * B_TOT + b];

    const size_t base = ((size_t)(n * T) * C + c) * HW + hw;
    float xv[T];
#pragma unroll
    for (int t = 0; t < T; ++t) xv[t] = x[base + (size_t)t * C * HW];

#pragma unroll
    for (int t = 0; t < T; ++t) {
        float acc = 0.f;
#pragma unroll
        for (int k = 0; k < KK; ++k) {
            const int j = t + k - 4;   // causal, zero-padded left
            if (j >= 0) acc = fmaf(w[t][k], xv[j], acc);
        }
        out[base + (size_t)t * C * HW] = acc;
    }
}

// ---------------------------------------------------------------------------
extern "C" void kernel_launch(void* const* d_in, const int* in_sizes, int n_in,
                              void* d_out, int out_size, void* d_ws, size_t ws_size,
                              hipStream_t stream) {
    const float* x = (const float*)d_in[0];   // (128, 512, 14, 14)
    const float* W = (const float*)d_in[1];   // (20, 512)
    float* out = (float*)d_out;               // (128, 512, 14, 14)

    float* wgt = (float*)d_ws;                // 160 * 3136 floats = 2 MB

    k_weights<<<dim3(NT * 4), 512, 0, stream>>>(x, W, wgt);   // 512 blocks
    k_conv<<<dim3((NSEG * C * HW) / 256), 256, 0, stream>>>(x, wgt, out);
}